// Round 5
// baseline (517.377 us; speedup 1.0000x reference)
//
#include <hip/hip_runtime.h>
#include <stdint.h>

// RNN car-following, 256 sequential steps x 4096 vehicles; 8 veh/WG, 512 WGs.
// Round-9: round-7 base (375us, best measured) + ONE isolated change:
//   ROLE ROTATION by block index. Waves map to SIMDs as wid%4, so both
//   co-resident blocks put their heavy chain wave on SIMD3; rotating roles
//   per block ((bid^(bid>>8))&3) separates the two chain waves onto
//   different SIMDs. (Round-8 bundled this with a bpermute chain rewrite
//   that regressed 11%; measured lesson: ds_bpermute reg-transposes are
//   NOT cheaper than the LDS round-trip on this chain. Unbundling.)
// Plus two zero-risk code motions on the chain: lead[] read hoisted off the
// dense tail (depends only on t), jpA+jpB pre-added before the MFMA tail.
// Structure (from round 7): ONE barrier/step; chain on role3:
//   Xcol -> conv1(rows 23,24) -> P -> conv2 fresh taps -> O2 -> dense jp4/jp5
//   -> rsum -> state -> Xcol'. Off-chain concurrent: role0 Jpart(t+1),
//   role1 j0(t+2)+flush, role2 row0(t+3).

#define PAST 25
#define NTW_MAX 280

typedef __attribute__((ext_vector_type(8))) short bf16x8;
typedef __attribute__((ext_vector_type(4))) float f32x4;
typedef unsigned short u16x2 __attribute__((ext_vector_type(2)));
#define MFMA16 __builtin_amdgcn_mfma_f32_16x16x32_bf16

static __device__ __forceinline__ uint32_t f2bf(float f) {
  union { float f; uint32_t u; } x; x.f = f;
  return (x.u + 0x7FFFu + ((x.u >> 16) & 1u)) >> 16;
}
static __device__ __forceinline__ float bf2f(uint32_t b) {
  union { uint32_t u; float f; } x; x.u = b << 16; return x.f;
}
// one-instruction RNE pack of two f32 -> packed bf16x2 (low=lo, high=hi)
static __device__ __forceinline__ uint32_t pkbf(float lo, float hi) {
  uint32_t r;
  asm("v_cvt_pk_bf16_f32 %0, %1, %2" : "=v"(r) : "v"(lo), "v"(hi));
  return r;
}
static __device__ __forceinline__ f32x4 bcast4(float v) { f32x4 r = {v, v, v, v}; return r; }

static __device__ __forceinline__ uint32_t pkmax(uint32_t a, uint32_t b) {
#if __has_builtin(__builtin_elementwise_max)
  union U { uint32_t w; u16x2 v; } x, y; x.w = a; y.w = b;
  x.v = __builtin_elementwise_max(x.v, y.v);
  return x.w;
#else
  uint32_t al = a << 16, bl = b << 16;
  uint32_t lo = (al > bl ? al : bl) >> 16;
  uint32_t ah = a & 0xffff0000u, bh = b & 0xffff0000u;
  uint32_t hi = ah > bh ? ah : bh;
  return lo | hi;
#endif
}
static __device__ __forceinline__ uint4 maxq(uint4 a, uint4 b) {
  uint4 r; r.x = pkmax(a.x, b.x); r.y = pkmax(a.y, b.y);
  r.z = pkmax(a.z, b.z); r.w = pkmax(a.w, b.w); return r;
}
static __device__ __forceinline__ int w21(int x) { if (x >= 21) x -= 21; if (x >= 21) x -= 21; return x; }
static __device__ __forceinline__ int w17(int x) { if (x >= 17) x -= 17; if (x >= 17) x -= 17; return x; }
static __device__ __forceinline__ void lds_fence() {
  asm volatile("s_waitcnt lgkmcnt(0)" ::: "memory");
}
// sum across each 16-lane row via DPP rotate-accumulate (row_ror 1/2/4/8).
static __device__ __forceinline__ float rsum16(float x) {
  x += __builtin_bit_cast(float, __builtin_amdgcn_update_dpp(0, __builtin_bit_cast(int, x), 0x121, 0xf, 0xf, true));
  x += __builtin_bit_cast(float, __builtin_amdgcn_update_dpp(0, __builtin_bit_cast(int, x), 0x122, 0xf, 0xf, true));
  x += __builtin_bit_cast(float, __builtin_amdgcn_update_dpp(0, __builtin_bit_cast(int, x), 0x124, 0xf, 0xf, true));
  x += __builtin_bit_cast(float, __builtin_amdgcn_update_dpp(0, __builtin_bit_cast(int, x), 0x128, 0xf, 0xf, true));
  return x;
}

union FragU { bf16x8 v; uint16_t u[8]; uint4 q; };
struct RowD { f32x4 d0, d1; };

// 2112 + 17920 + 12288 + 20480 + 8192 + 2048 + 2048 = 65088 B  (<= 65536)
struct __align__(16) SMem {
  uint32_t Xcol[8][33][2];    // x-column ring (u&31): c0 = x0hi|x1<<16, c1 = x2|x0lo<<16
  float2 lead[8][NTW_MAX];    // full lead stream (preloaded once)
  uint16_t P[24 * 8 * 32];    // pooled conv1: ring 0..20 ((pos)%21), 21/23 = row0 dbuf, 22 = row12
  uint16_t O2[20 * 8 * 64];   // out2: ring 0..16, 17/18 = j0 dbuf, 19 = j10
  float2 obuf[2][8][64];      // output dbuf (flushed every 64 steps)
  f32x4 JpartA[2][64];        // jp0..jp3 partial dense acc (hf=0), dbuf by t&1
  f32x4 JpartB[2][64];        // jp0..jp3 partial dense acc (hf=1)
};

__global__ __launch_bounds__(256, 2) void rnncf_kernel(
    const float* __restrict__ lead_states, const float* __restrict__ cur_states,
    const float* __restrict__ conv1_w, const float* __restrict__ conv1_b,
    const float* __restrict__ conv2_w, const float* __restrict__ conv2_b,
    const float* __restrict__ dense2_w, const float* __restrict__ dense2_b,
    const float* __restrict__ dense1_w, const float* __restrict__ dense1_b,
    float* __restrict__ out, int nt, int ntw) {
  __shared__ SMem sm;
  const int tid = threadIdx.x;
  const int lane = tid & 63;
  const int wid = tid >> 6;           // 0..3
  const int n = lane & 15;
  const int quad = lane >> 4;
  const int vbase = blockIdx.x * 8;
  // role rotation: spread the heavy (role 3) chain wave across SIMDs for the
  // two co-resident blocks, whichever co-residency pattern (b,b+1 or b,b+256).
  const int role = (wid + (int)((blockIdx.x ^ (blockIdx.x >> 8)) & 3)) & 3;

  // ---------------- phase 0: Xcol ring + lead preload + state ----------------
  if (tid < 200) {
    int v = tid & 7, u = tid >> 3;
    const float2 l = *(const float2*)(lead_states + ((size_t)(vbase + v) * ntw + u) * 2);
    const float2 c = *(const float2*)(cur_states + ((size_t)(vbase + v) * PAST + u) * 2);
    float x0 = (l.x - c.x) * 0.005f;
    uint32_t w0 = pkbf(x0, c.y * 0.025f);
    sm.Xcol[v][u][0] = w0;
    sm.Xcol[v][u][1] = pkbf(l.y * 0.025f, x0 - bf2f(w0 & 0xffffu));
  }
#pragma unroll
  for (int v = 0; v < 8; ++v)
    for (int i = tid; i < ntw; i += 256)
      sm.lead[v][i] = *(const float2*)(lead_states + ((size_t)(vbase + v) * ntw + i) * 2);

  float pos_s = 0.f, spd_s = 0.f;
  if (role == 3 && quad < 2 && n < 4) {   // state lives on the chain wave
    int veh = quad * 4 + n;
    const float2 c = *(const float2*)(cur_states + ((size_t)(vbase + veh) * PAST + 24) * 2);
    pos_s = c.x * 0.005f; spd_s = c.y * 0.025f;
  }

  // ---------------- weight fragments ----------------
  FragU B1[2];
#pragma unroll
  for (int ct = 0; ct < 2; ++ct)
#pragma unroll
    for (int jj = 0; jj < 8; ++jj) {
      int k = quad * 8 + jj;
      int dw = k & 3, cig = (k >> 2) & 3;
      float w = 0.f;
      if (k < 16 && dw < 3) {
        int ci = (cig == 3) ? 0 : cig;
        w = conv1_w[(dw * 3 + ci) * 32 + ct * 16 + n];
      }
      B1[ct].u[jj] = (uint16_t)f2bf(w);
    }
  FragU B2[3][4];
#pragma unroll
  for (int dw = 0; dw < 3; ++dw)
#pragma unroll
    for (int ct = 0; ct < 4; ++ct)
#pragma unroll
      for (int jj = 0; jj < 8; ++jj) {
        int kap = quad * 8 + jj;
        int ci = (kap & 1) * 16 + (kap >> 1);
        B2[dw][ct].u[jj] = (uint16_t)f2bf(conv2_w[(dw * 32 + ci) * 64 + ct * 16 + n]);
      }
  FragU Bd[12];
#pragma unroll
  for (int kt = 0; kt < 12; ++kt)
#pragma unroll
    for (int jj = 0; jj < 8; ++jj) {
      int flat = kt * 32 + quad * 8 + jj;
      int jp = flat >> 6, kap = flat & 63;
      int co = (kap & 3) * 16 + (kap >> 2);
      Bd[kt].u[jj] = (uint16_t)f2bf((n < 10) ? dense2_w[(jp * 64 + co) * 10 + n] : 0.f);
    }
  const float b1v0 = conv1_b[n], b1v1 = conv1_b[16 + n];
  float b2v[4];
#pragma unroll
  for (int ct = 0; ct < 4; ++ct) b2v[ct] = conv2_b[ct * 16 + n];
  const float d2bv = (n < 10) ? dense2_b[n] : 0.f;
  const float wd1v = (n < 10) ? dense1_w[n] : 0.f;
  const float bd1v = dense1_b[0];

  // ---------------- helpers ----------------
  auto pIdx = [&](int s, int veh, int ch) { return ((s * 8 + veh) * 4 + ch) * 8; };
  auto oIdx = [&](int s, int veh, int ch) { return ((s * 8 + veh) * 8 + ch) * 8; };

  auto build_x = [&](int c, int padL, int padR) -> FragU {
    int h = quad & 1, v8 = n & 7;
    uint32_t d0 = padL ? 0u : sm.Xcol[v8][(c - 1) & 31][h];
    uint32_t d1 = sm.Xcol[v8][c & 31][h];
    uint32_t d2 = padR ? 0u : sm.Xcol[v8][(c + 1) & 31][h];
    FragU a;
    a.q.x = __builtin_amdgcn_perm(d1, d0, 0x05040100u);
    a.q.y = d2 & 0xffffu;
    a.q.z = __builtin_amdgcn_perm(d1, d0, 0x07060302u);
    a.q.w = d2 >> 16;
    return a;
  };

  auto conv1_row = [&](int c, int padL, int padR) -> RowD {
    FragU a = build_x(c, padL, padR);
    RowD rd;
    rd.d0 = MFMA16(a.v, B1[0].v, bcast4(b1v0), 0, 0, 0);
    rd.d1 = MFMA16(a.v, B1[1].v, bcast4(b1v1), 0, 0, 0);
    return rd;
  };

  auto pool_write = [&](const RowD& A, const RowD& Bq, int ds) {
    if (quad < 2) {
#pragma unroll
      for (int r = 0; r < 4; ++r) {
        float e0 = fmaxf(fmaxf(A.d0[r], Bq.d0[r]), 0.f);
        float e1 = fmaxf(fmaxf(A.d1[r], Bq.d1[r]), 0.f);
        int veh = quad * 4 + r;
        *(uint32_t*)&sm.P[pIdx(ds, veh, (n >> 2) ^ (veh & 3)) + (n & 3) * 2] = pkbf(e0, e1);
      }
    }
  };

  auto pool_write1 = [&](const RowD& A, int ds) {
    if (quad < 2) {
#pragma unroll
      for (int r = 0; r < 4; ++r) {
        float e0 = fmaxf(A.d0[r], 0.f), e1 = fmaxf(A.d1[r], 0.f);
        int veh = quad * 4 + r;
        *(uint32_t*)&sm.P[pIdx(ds, veh, (n >> 2) ^ (veh & 3)) + (n & 3) * 2] = pkbf(e0, e1);
      }
    }
  };

  auto ld_P = [&](int s) -> FragU {
    FragU a; a.q = *(const uint4*)&sm.P[pIdx(s, n & 7, quad ^ (n & 3))]; return a;
  };

  auto conv2_acc = [&](f32x4* acc, int slot, int dw) {
    FragU a = ld_P(slot);
#pragma unroll
    for (int ct = 0; ct < 4; ++ct) acc[ct] = MFMA16(a.v, B2[dw][ct].v, acc[ct], 0, 0, 0);
  };

  auto conv2_accf = [&](f32x4* acc, const FragU& a, int dw) {
#pragma unroll
    for (int ct = 0; ct < 4; ++ct) acc[ct] = MFMA16(a.v, B2[dw][ct].v, acc[ct], 0, 0, 0);
  };

  auto o2_write = [&](const f32x4* acc, int ds) {
    if (quad < 2) {
#pragma unroll
      for (int r = 0; r < 4; ++r) {
        int veh = quad * 4 + r;
        float m0 = fmaxf(acc[0][r], 0.f), m1 = fmaxf(acc[1][r], 0.f);
        float m2 = fmaxf(acc[2][r], 0.f), m3 = fmaxf(acc[3][r], 0.f);
        uint2 w2; w2.x = pkbf(m0, m1); w2.y = pkbf(m2, m3);
        *(uint2*)&sm.O2[oIdx(ds, veh, (n >> 1) ^ (veh & 7)) + (n & 1) * 4] = w2;
      }
    }
  };

  auto dense_jp = [&](int pa, int pb, int jp, f32x4& a0, f32x4& a1) {
#pragma unroll
    for (int hf = 0; hf < 2; ++hf) {
      uint4 qa = *(const uint4*)&sm.O2[oIdx(pa, n & 7, (hf * 4 + quad) ^ (n & 7))];
      if (pb >= 0) {
        uint4 qb = *(const uint4*)&sm.O2[oIdx(pb, n & 7, (hf * 4 + quad) ^ (n & 7))];
        qa = maxq(qa, qb);
      }
      FragU a; a.q = qa;
      if (hf == 0) a0 = MFMA16(a.v, Bd[jp * 2].v, a0, 0, 0, 0);
      else         a1 = MFMA16(a.v, Bd[jp * 2 + 1].v, a1, 0, 0, 0);
    }
  };

  auto dense_jp_pre = [&](int pa, const uint4* qpre, int jp, f32x4& a0, f32x4& a1) {
#pragma unroll
    for (int hf = 0; hf < 2; ++hf) {
      uint4 qa = *(const uint4*)&sm.O2[oIdx(pa, n & 7, (hf * 4 + quad) ^ (n & 7))];
      if (qpre) qa = maxq(qa, qpre[hf]);
      FragU a; a.q = qa;
      if (hf == 0) a0 = MFMA16(a.v, Bd[jp * 2].v, a0, 0, 0, 0);
      else         a1 = MFMA16(a.v, Bd[jp * 2 + 1].v, a1, 0, 0, 0);
    }
  };

  auto flush_out = [&](int bi, int t0, int cnt) {
    int vv = lane >> 3;
    int s0 = (lane & 7) * 8;
#pragma unroll
    for (int k = 0; k < 8; ++k) {
      int s = s0 + k;
      if (s < cnt) {
        float2 d = sm.obuf[bi][vv][s];
        *(float2*)(out + ((size_t)(vbase + vv) * nt + t0 + s) * 2) = d;
      }
    }
  };

  __syncthreads();

  // ---------------- phase 1: P ring init pos=2..21 ----------------
#pragma unroll
  for (int i = 0; i < 5; ++i) {
    int g = 2 + wid + 4 * i;
    RowD A = conv1_row(g, 0, 0);
    RowD Bq = conv1_row(g + 1, 0, 0);
    pool_write(A, Bq, g % 21);
  }
  __syncthreads();

  // ---------------- phase 2: O2 ring init a=2..17 ----------------
#pragma unroll
  for (int i = 0; i < 4; ++i) {
    int a = 2 + wid + 4 * i;
    f32x4 acc[4];
#pragma unroll
    for (int ct = 0; ct < 4; ++ct) acc[ct] = bcast4(b2v[ct]);
    conv2_acc(acc, a % 21, 0);
    conv2_acc(acc, (a + 2) % 21, 1);
    conv2_acc(acc, (a + 4) % 21, 2);
    o2_write(acc, a % 17);
  }
  __syncthreads();

  // ---------------- prologue A: j0(0)->17, j0(1)->18, row0(2)->21, chain accs ----
  RowD c1A = {};
  f32x4 accA[4] = {}, accB[4] = {};
  if (role == 1) {
    RowD A = conv1_row(0, 1, 0), Bq = conv1_row(1, 0, 0);
    pool_write(A, Bq, 23);          // scratch (row0(0))
    lds_fence();
    f32x4 aj[4];
#pragma unroll
    for (int ct = 0; ct < 4; ++ct) aj[ct] = bcast4(b2v[ct]);
    conv2_acc(aj, 23, 0); conv2_acc(aj, 2, 1); conv2_acc(aj, 4, 2);
    o2_write(aj, 17);               // j0(0)
  } else if (role == 2) {
    RowD A = conv1_row(1, 1, 0), Bq = conv1_row(2, 0, 0);
    pool_write(A, Bq, 1);           // scratch (row0(1)); ring slot 1 unused until step 0
    lds_fence();
    f32x4 aj[4];
#pragma unroll
    for (int ct = 0; ct < 4; ++ct) aj[ct] = bcast4(b2v[ct]);
    conv2_acc(aj, 1, 0); conv2_acc(aj, 3, 1); conv2_acc(aj, 5, 2);
    o2_write(aj, 18);               // j0(1)
  } else if (role == 0) {
    RowD A = conv1_row(2, 1, 0), Bq = conv1_row(3, 0, 0);
    pool_write(A, Bq, 21);          // row0(2) -> R0(even)
  } else {
#pragma unroll
    for (int ct = 0; ct < 4; ++ct) accA[ct] = bcast4(b2v[ct]);
    conv2_acc(accA, 18, 0);         // j9(0) dw0
    conv2_acc(accA, 20, 1);         // j9(0) dw1
#pragma unroll
    for (int ct = 0; ct < 4; ++ct) accB[ct] = bcast4(b2v[ct]);
    conv2_acc(accB, 20, 0);         // j10(0) dw0
    c1A = conv1_row(22, 0, 0);
  }
  __syncthreads();

  // ---------------- prologue B: Jpart(0) ----------------
  if (role == 0) {
    f32x4 a0 = bcast4(d2bv), a1 = bcast4(0.f);
    dense_jp(17, 2, 0, a0, a1);     // jp0 = max(j0(0), j1(0))
    dense_jp(4, 6, 1, a0, a1);
    dense_jp(8, 10, 2, a0, a1);
    dense_jp(12, 14, 3, a0, a1);
    sm.JpartA[0][lane] = a0;
    sm.JpartB[0][lane] = a1;
  }
  __syncthreads();

  // ---------------- sequential steps (ONE barrier each) ----------------
  int tm21 = 0, tm17 = 0;
  for (int t = 0; t < nt; ++t) {
    const int sP22 = w21(tm21 + 22);
    const int sO16 = w17(tm17 + 16), sO18 = w17(tm17 + 18);
    const int tm21n = (tm21 + 1 == 21) ? 0 : tm21 + 1;
    const int tm17n = (tm17 + 1 == 17) ? 0 : tm17 + 1;
    const int sP18n = w21(tm21n + 18), sP20n = w21(tm21n + 20);

    if (role == 3) {
      // ---- early off-chain loads (latency hidden under conv1) ----
      f32x4 jpA = sm.JpartA[t & 1][lane];
      f32x4 jpB = sm.JpartB[t & 1][lane];
      uint4 qj8[2];
#pragma unroll
      for (int hf = 0; hf < 2; ++hf)
        qj8[hf] = *(const uint4*)&sm.O2[oIdx(sO16, n & 7, (hf * 4 + quad) ^ (n & 7))];
      FragU fA18 = ld_P(sP18n);     // for accA(t+1) dw0
      FragU fA20 = ld_P(sP20n);     // for accA(t+1) dw1 / accB(t+1) dw0
      float2 ln = {0.f, 0.f};       // lead read hoisted off the dense tail
      int ui = t + PAST; if (ui > ntw - 1) ui = ntw - 1;
      if (quad < 2 && n < 4) ln = sm.lead[quad * 4 + n][ui];
      f32x4 jpS = jpA + jpB;
      // ---- fresh conv1 ----
      RowD Bq = conv1_row(t + 23, 0, 0);      // needs col t+24 (written step t-1)
      RowD Sg = conv1_row(t + 24, 0, 1);
      pool_write(c1A, Bq, sP22);              // row 11 -> ring
      pool_write1(Sg, 22);                    // row 12
      c1A = Bq;                               // free carry for step t+1
      lds_fence();
      // ---- fresh conv2 taps (dw0/dw1 carried from last step) ----
      conv2_acc(accA, sP22, 2);               // j9 complete
      conv2_acc(accB, sP22, 1);
      conv2_acc(accB, 22, 2);                 // j10 complete
      o2_write(accA, sO18);                   // j9 -> ring
      o2_write(accB, 19);                     // j10 -> slot 19
      lds_fence();
      // ---- fresh dense + reduce + state ----
      f32x4 acc2 = bcast4(0.f), acc3 = bcast4(0.f);
      f32x4 acc4 = bcast4(0.f), acc5 = bcast4(0.f);
      dense_jp_pre(sO18, qj8, 4, acc2, acc3);                 // jp4 = max(j8, j9)
      dense_jp_pre(19, (const uint4*)nullptr, 5, acc4, acc5); // jp5 = j10
      float s0 = fmaxf(jpS[0] + acc2[0] + acc3[0] + acc4[0] + acc5[0], 0.f) * wd1v;
      float s1 = fmaxf(jpS[1] + acc2[1] + acc3[1] + acc4[1] + acc5[1], 0.f) * wd1v;
      float s2 = fmaxf(jpS[2] + acc2[2] + acc3[2] + acc4[2] + acc5[2], 0.f) * wd1v;
      float s3 = fmaxf(jpS[3] + acc2[3] + acc3[3] + acc4[3] + acc5[3], 0.f) * wd1v;
      s0 = rsum16(s0); s1 = rsum16(s1); s2 = rsum16(s2); s3 = rsum16(s3);
      if (quad < 2 && n < 4) {
        int veh = quad * 4 + n;
        float sv = (n == 0) ? s0 : (n == 1) ? s1 : (n == 2) ? s2 : s3;
        float accv = 10.f * (sv + bd1v) - 6.f;            // (MAXA-MINA)*x + MINA
        float np_s = pos_s + 0.02f * spd_s;               // scaled pos + DT*spd
        float nsp = spd_s * 40.f + 0.1f * accv;           // raw new speed
        pos_s = np_s; spd_s = nsp * 0.025f;
        float2 o2v; o2v.x = np_s * 200.f; o2v.y = nsp;
        sm.obuf[(t >> 6) & 1][veh][t & 63] = o2v;
        float x0 = ln.x * 0.005f - np_s;
        uint32_t wlo = pkbf(x0, spd_s);
        sm.Xcol[veh][(t + PAST) & 31][0] = wlo;
        sm.Xcol[veh][(t + PAST) & 31][1] = pkbf(ln.y * 0.025f, x0 - bf2f(wlo & 0xffffu));
      }
      // ---- next-step partial accs: register MFMA tail (loads hoisted above) ----
#pragma unroll
      for (int ct = 0; ct < 4; ++ct) accA[ct] = bcast4(b2v[ct]);
      conv2_accf(accA, fA18, 0);
      conv2_accf(accA, fA20, 1);
#pragma unroll
      for (int ct = 0; ct < 4; ++ct) accB[ct] = bcast4(b2v[ct]);
      conv2_accf(accB, fA20, 0);
    } else if (role == 0) {
      // Jpart(t+1) = bias + jp0..jp3 (all operands >= 2 steps old)
      f32x4 a0 = bcast4(d2bv), a1 = bcast4(0.f);
      dense_jp(17 + ((t + 1) & 1), w17(tm17n + 2), 0, a0, a1);  // jp0 = max(j0, j1)
      dense_jp(w17(tm17n + 4), w17(tm17n + 6), 1, a0, a1);
      dense_jp(w17(tm17n + 8), w17(tm17n + 10), 2, a0, a1);
      dense_jp(w17(tm17n + 12), w17(tm17n + 14), 3, a0, a1);
      sm.JpartA[(t + 1) & 1][lane] = a0;
      sm.JpartB[(t + 1) & 1][lane] = a1;
    } else if (role == 1) {
      // j0(t+2): row0 from R0 dbuf (written by role2 last step) + old ring rows
      if ((t & 63) == 0 && t > 0) flush_out(((t >> 6) & 1) ^ 1, t - 64, 64);
      f32x4 aj[4];
#pragma unroll
      for (int ct = 0; ct < 4; ++ct) aj[ct] = bcast4(b2v[ct]);
      conv2_acc(aj, (t & 1) ? 23 : 21, 0);     // R0(t+2)
      conv2_acc(aj, w21(tm21 + 4), 1);
      conv2_acc(aj, w21(tm21 + 6), 2);
      o2_write(aj, 17 + (t & 1));              // J0(t+2)
    } else {
      // row0(t+3) -> R0 dbuf (cols t+2..t+5, all old)
      RowD A = conv1_row(t + 3, 1, 0);
      RowD Bq = conv1_row(t + 4, 0, 0);
      pool_write(A, Bq, (t & 1) ? 21 : 23);    // R0(t+3)
    }
    __syncthreads();

    tm21 = tm21n; tm17 = tm17n;
  }

  // final output flush
  if (role == 1) {
    int t0 = (nt - 1) & ~63;
    flush_out(((nt - 1) >> 6) & 1, t0, nt - t0);
  }
}

extern "C" void kernel_launch(void* const* d_in, const int* in_sizes, int n_in,
                              void* d_out, int out_size, void* d_ws, size_t ws_size,
                              hipStream_t stream) {
  const float* lead = (const float*)d_in[0];
  const float* cur  = (const float*)d_in[1];
  // d_in[2] = mask (unused by reference)
  const float* c1w = (const float*)d_in[3];
  const float* c1b = (const float*)d_in[4];
  const float* c2w = (const float*)d_in[5];
  const float* c2b = (const float*)d_in[6];
  const float* d2w = (const float*)d_in[7];
  const float* d2b = (const float*)d_in[8];
  const float* d1w = (const float*)d_in[9];
  const float* d1b = (const float*)d_in[10];
  float* out = (float*)d_out;

  int nveh = in_sizes[1] / (PAST * 2);   // 4096
  int ntw  = in_sizes[2] / nveh;         // nt + PAST - 1 (<= NTW_MAX)
  int nt   = ntw - PAST + 1;             // 256
  int nblocks = nveh / 8;                // 512

  rnncf_kernel<<<nblocks, 256, 0, stream>>>(lead, cur, c1w, c1b, c2w, c2b,
                                            d2w, d2b, d1w, d1b, out, nt, ntw);
}

// Round 6
// 403.524 us; speedup vs baseline: 1.2821x; 1.2821x over previous
//
#include <hip/hip_runtime.h>
#include <stdint.h>

// RNN car-following, 256 sequential steps x 4096 vehicles; 8 veh/WG, 512 WGs.
// Round-10: R7 base (375us best) + ONLY the swapped-conv1/bpermute chain.
// A/B record: R7(LDS chain, no rot)=375; R8(rot+bperm+micros)=417;
// R9(rot+micros, LDS chain)=457  =>  bpermute chain = -40us (R8 vs R9),
// rotation+micros = +82us (R9 vs R7, spill signature: FETCH/WRITE +2/+3.5MB
// at the 128-VGPR launch_bounds cap). So: NO rotation, NO ln hoist, and the
// chain computes conv1 operand-SWAPPED (mfma(B1,X)) so the conv2 A-fragment
// comes from 4 ds_bpermute (shared index) in registers:
//   - fence #1 (pool_write -> lgkmcnt0 -> ld_P) eliminated from the chain
//   - pooled row 12 never touches LDS; row 11 ring write stays (unfenced,
//     barrier-ordered for its >=2-step-later readers, bit-identical format)
// Structure (R7): ONE barrier/step; chain on wid3; off-chain concurrent:
//   wid0 Jpart(t+1), wid1 j0(t+2)+flush, wid2 row0(t+3).

#define PAST 25
#define NTW_MAX 280

typedef __attribute__((ext_vector_type(8))) short bf16x8;
typedef __attribute__((ext_vector_type(4))) float f32x4;
typedef unsigned short u16x2 __attribute__((ext_vector_type(2)));
#define MFMA16 __builtin_amdgcn_mfma_f32_16x16x32_bf16

static __device__ __forceinline__ uint32_t f2bf(float f) {
  union { float f; uint32_t u; } x; x.f = f;
  return (x.u + 0x7FFFu + ((x.u >> 16) & 1u)) >> 16;
}
static __device__ __forceinline__ float bf2f(uint32_t b) {
  union { uint32_t u; float f; } x; x.u = b << 16; return x.f;
}
// one-instruction RNE pack of two f32 -> packed bf16x2 (low=lo, high=hi)
static __device__ __forceinline__ uint32_t pkbf(float lo, float hi) {
  uint32_t r;
  asm("v_cvt_pk_bf16_f32 %0, %1, %2" : "=v"(r) : "v"(lo), "v"(hi));
  return r;
}
static __device__ __forceinline__ f32x4 bcast4(float v) { f32x4 r = {v, v, v, v}; return r; }

static __device__ __forceinline__ uint32_t pkmax(uint32_t a, uint32_t b) {
#if __has_builtin(__builtin_elementwise_max)
  union U { uint32_t w; u16x2 v; } x, y; x.w = a; y.w = b;
  x.v = __builtin_elementwise_max(x.v, y.v);
  return x.w;
#else
  uint32_t al = a << 16, bl = b << 16;
  uint32_t lo = (al > bl ? al : bl) >> 16;
  uint32_t ah = a & 0xffff0000u, bh = b & 0xffff0000u;
  uint32_t hi = ah > bh ? ah : bh;
  return lo | hi;
#endif
}
static __device__ __forceinline__ uint4 maxq(uint4 a, uint4 b) {
  uint4 r; r.x = pkmax(a.x, b.x); r.y = pkmax(a.y, b.y);
  r.z = pkmax(a.z, b.z); r.w = pkmax(a.w, b.w); return r;
}
static __device__ __forceinline__ int w21(int x) { if (x >= 21) x -= 21; if (x >= 21) x -= 21; return x; }
static __device__ __forceinline__ int w17(int x) { if (x >= 17) x -= 17; if (x >= 17) x -= 17; return x; }
static __device__ __forceinline__ void lds_fence() {
  asm volatile("s_waitcnt lgkmcnt(0)" ::: "memory");
}
// sum across each 16-lane row via DPP rotate-accumulate (row_ror 1/2/4/8).
static __device__ __forceinline__ float rsum16(float x) {
  x += __builtin_bit_cast(float, __builtin_amdgcn_update_dpp(0, __builtin_bit_cast(int, x), 0x121, 0xf, 0xf, true));
  x += __builtin_bit_cast(float, __builtin_amdgcn_update_dpp(0, __builtin_bit_cast(int, x), 0x122, 0xf, 0xf, true));
  x += __builtin_bit_cast(float, __builtin_amdgcn_update_dpp(0, __builtin_bit_cast(int, x), 0x124, 0xf, 0xf, true));
  x += __builtin_bit_cast(float, __builtin_amdgcn_update_dpp(0, __builtin_bit_cast(int, x), 0x128, 0xf, 0xf, true));
  return x;
}

union FragU { bf16x8 v; uint16_t u[8]; uint4 q; };
struct RowD { f32x4 d0, d1; };   // swapped conv1 out: lane=veh, regs=ch quad*4+r

// 2112 + 17920 + 12288 + 20480 + 8192 + 2048 + 2048 = 65088 B  (<= 65536)
struct __align__(16) SMem {
  uint32_t Xcol[8][33][2];    // x-column ring (u&31): c0 = x0hi|x1<<16, c1 = x2|x0lo<<16
  float2 lead[8][NTW_MAX];    // full lead stream (preloaded once)
  uint16_t P[24 * 8 * 32];    // pooled conv1: ring 0..20, 21/23 = row0 dbuf, 22 unused
  uint16_t O2[20 * 8 * 64];   // out2: ring 0..16, 17/18 = j0 dbuf, 19 = j10
  float2 obuf[2][8][64];      // output dbuf (flushed every 64 steps)
  f32x4 JpartA[2][64];        // jp0..jp3 partial dense acc (hf=0), dbuf by t&1
  f32x4 JpartB[2][64];        // jp0..jp3 partial dense acc (hf=1)
};

__global__ __launch_bounds__(256, 2) void rnncf_kernel(
    const float* __restrict__ lead_states, const float* __restrict__ cur_states,
    const float* __restrict__ conv1_w, const float* __restrict__ conv1_b,
    const float* __restrict__ conv2_w, const float* __restrict__ conv2_b,
    const float* __restrict__ dense2_w, const float* __restrict__ dense2_b,
    const float* __restrict__ dense1_w, const float* __restrict__ dense1_b,
    float* __restrict__ out, int nt, int ntw) {
  __shared__ SMem sm;
  const int tid = threadIdx.x;
  const int lane = tid & 63;
  const int wid = tid >> 6;           // 0..3 (no rotation -- R9 measured it as a spill-regression)
  const int n = lane & 15;
  const int quad = lane >> 4;
  const int vbase = blockIdx.x * 8;
  // bpermute index for pooled-row reg->frag transpose: target lane l reads
  // source lane quad*16 + (l&7)  (byte address).
  const int bpidx = ((lane >> 4) << 6) | ((lane & 7) << 2);

  // ---------------- phase 0: Xcol ring + lead preload + state ----------------
  if (tid < 200) {
    int v = tid & 7, u = tid >> 3;
    const float2 l = *(const float2*)(lead_states + ((size_t)(vbase + v) * ntw + u) * 2);
    const float2 c = *(const float2*)(cur_states + ((size_t)(vbase + v) * PAST + u) * 2);
    float x0 = (l.x - c.x) * 0.005f;
    uint32_t w0 = pkbf(x0, c.y * 0.025f);
    sm.Xcol[v][u][0] = w0;
    sm.Xcol[v][u][1] = pkbf(l.y * 0.025f, x0 - bf2f(w0 & 0xffffu));
  }
#pragma unroll
  for (int v = 0; v < 8; ++v)
    for (int i = tid; i < ntw; i += 256)
      sm.lead[v][i] = *(const float2*)(lead_states + ((size_t)(vbase + v) * ntw + i) * 2);

  float pos_s = 0.f, spd_s = 0.f;
  if (wid == 3 && quad < 2 && n < 4) {   // state lives on the chain wave
    int veh = quad * 4 + n;
    const float2 c = *(const float2*)(cur_states + ((size_t)(vbase + veh) * PAST + 24) * 2);
    pos_s = c.x * 0.005f; spd_s = c.y * 0.025f;
  }

  // ---------------- weight fragments ----------------
  FragU B1[2];
#pragma unroll
  for (int ct = 0; ct < 2; ++ct)
#pragma unroll
    for (int jj = 0; jj < 8; ++jj) {
      int k = quad * 8 + jj;
      int dw = k & 3, cig = (k >> 2) & 3;
      float w = 0.f;
      if (k < 16 && dw < 3) {
        int ci = (cig == 3) ? 0 : cig;
        w = conv1_w[(dw * 3 + ci) * 32 + ct * 16 + n];
      }
      B1[ct].u[jj] = (uint16_t)f2bf(w);
    }
  FragU B2[3][4];
#pragma unroll
  for (int dw = 0; dw < 3; ++dw)
#pragma unroll
    for (int ct = 0; ct < 4; ++ct)
#pragma unroll
      for (int jj = 0; jj < 8; ++jj) {
        int kap = quad * 8 + jj;
        int ci = (kap & 1) * 16 + (kap >> 1);
        B2[dw][ct].u[jj] = (uint16_t)f2bf(conv2_w[(dw * 32 + ci) * 64 + ct * 16 + n]);
      }
  FragU Bd[12];
#pragma unroll
  for (int kt = 0; kt < 12; ++kt)
#pragma unroll
    for (int jj = 0; jj < 8; ++jj) {
      int flat = kt * 32 + quad * 8 + jj;
      int jp = flat >> 6, kap = flat & 63;
      int co = (kap & 3) * 16 + (kap >> 2);
      Bd[kt].u[jj] = (uint16_t)f2bf((n < 10) ? dense2_w[(jp * 64 + co) * 10 + n] : 0.f);
    }
  // swapped conv1 bias: lane holds output channels quad*4+r (r=0..3)
  f32x4 b1q0, b1q1;
#pragma unroll
  for (int r = 0; r < 4; ++r) {
    b1q0[r] = conv1_b[quad * 4 + r];
    b1q1[r] = conv1_b[16 + quad * 4 + r];
  }
  float b2v[4];
#pragma unroll
  for (int ct = 0; ct < 4; ++ct) b2v[ct] = conv2_b[ct * 16 + n];
  const float d2bv = (n < 10) ? dense2_b[n] : 0.f;
  const float wd1v = (n < 10) ? dense1_w[n] : 0.f;
  const float bd1v = dense1_b[0];

  // ---------------- helpers ----------------
  auto pIdx = [&](int s, int veh, int ch) { return ((s * 8 + veh) * 4 + ch) * 8; };
  auto oIdx = [&](int s, int veh, int ch) { return ((s * 8 + veh) * 8 + ch) * 8; };

  auto build_x = [&](int c, int padL, int padR) -> FragU {
    int h = quad & 1, v8 = n & 7;
    uint32_t d0 = padL ? 0u : sm.Xcol[v8][(c - 1) & 31][h];
    uint32_t d1 = sm.Xcol[v8][c & 31][h];
    uint32_t d2 = padR ? 0u : sm.Xcol[v8][(c + 1) & 31][h];
    FragU a;
    a.q.x = __builtin_amdgcn_perm(d1, d0, 0x05040100u);
    a.q.y = d2 & 0xffffu;
    a.q.z = __builtin_amdgcn_perm(d1, d0, 0x07060302u);
    a.q.w = d2 >> 16;
    return a;
  };

  // swapped conv1: D = mfma(B1, X) -> lane = veh (l&7, dup at 8..15 per quad),
  // regs r = output channels quad*4+r (d0: ch<16, d1: ch>=16).
  auto conv1s_row = [&](int c, int padL, int padR) -> RowD {
    FragU a = build_x(c, padL, padR);
    RowD rd;
    rd.d0 = MFMA16(B1[0].v, a.v, b1q0, 0, 0, 0);
    rd.d1 = MFMA16(B1[1].v, a.v, b1q1, 0, 0, 0);
    return rd;
  };

  auto relumax4 = [&](const f32x4& a, const f32x4& b) -> f32x4 {
    f32x4 r;
#pragma unroll
    for (int i = 0; i < 4; ++i) r[i] = fmaxf(fmaxf(a[i], b[i]), 0.f);
    return r;
  };
  auto relu4 = [&](const f32x4& a) -> f32x4 {
    f32x4 r;
#pragma unroll
    for (int i = 0; i < 4; ++i) r[i] = fmaxf(a[i], 0.f);
    return r;
  };
  // pack pooled swapped row: word p = (ct0 ch 4q+p, ct1 ch 4q+p) = the
  // P-layout group (g = q^(v&3)) uint4, bit-identical to the legacy format.
  auto pack4 = [&](const f32x4& p0, const f32x4& p1) -> uint4 {
    uint4 w;
    w.x = pkbf(p0[0], p1[0]); w.y = pkbf(p0[1], p1[1]);
    w.z = pkbf(p0[2], p1[2]); w.w = pkbf(p0[3], p1[3]);
    return w;
  };
  auto p_store = [&](const uint4& w, int ds) {
    if (n < 8) *(uint4*)&sm.P[pIdx(ds, n, quad ^ (n & 3))] = w;
  };
  auto pool_store = [&](const RowD& A, const RowD& Bq, int ds) {
    p_store(pack4(relumax4(A.d0, Bq.d0), relumax4(A.d1, Bq.d1)), ds);
  };
  // reg->frag transpose: 4 bpermutes, shared index (== ld_P content, verified)
  auto bperm_frag = [&](const uint4& w) -> FragU {
    FragU f;
    f.q.x = (uint32_t)__builtin_amdgcn_ds_bpermute(bpidx, (int)w.x);
    f.q.y = (uint32_t)__builtin_amdgcn_ds_bpermute(bpidx, (int)w.y);
    f.q.z = (uint32_t)__builtin_amdgcn_ds_bpermute(bpidx, (int)w.z);
    f.q.w = (uint32_t)__builtin_amdgcn_ds_bpermute(bpidx, (int)w.w);
    return f;
  };

  auto ld_P = [&](int s) -> FragU {
    FragU a; a.q = *(const uint4*)&sm.P[pIdx(s, n & 7, quad ^ (n & 3))]; return a;
  };

  auto conv2_acc = [&](f32x4* acc, int slot, int dw) {
    FragU a = ld_P(slot);
#pragma unroll
    for (int ct = 0; ct < 4; ++ct) acc[ct] = MFMA16(a.v, B2[dw][ct].v, acc[ct], 0, 0, 0);
  };

  auto conv2_accf = [&](f32x4* acc, const FragU& a, int dw) {
#pragma unroll
    for (int ct = 0; ct < 4; ++ct) acc[ct] = MFMA16(a.v, B2[dw][ct].v, acc[ct], 0, 0, 0);
  };

  auto o2_write = [&](const f32x4* acc, int ds) {
    if (quad < 2) {
#pragma unroll
      for (int r = 0; r < 4; ++r) {
        int veh = quad * 4 + r;
        float m0 = fmaxf(acc[0][r], 0.f), m1 = fmaxf(acc[1][r], 0.f);
        float m2 = fmaxf(acc[2][r], 0.f), m3 = fmaxf(acc[3][r], 0.f);
        uint2 w2; w2.x = pkbf(m0, m1); w2.y = pkbf(m2, m3);
        *(uint2*)&sm.O2[oIdx(ds, veh, (n >> 1) ^ (veh & 7)) + (n & 1) * 4] = w2;
      }
    }
  };

  auto dense_jp = [&](int pa, int pb, int jp, f32x4& a0, f32x4& a1) {
#pragma unroll
    for (int hf = 0; hf < 2; ++hf) {
      uint4 qa = *(const uint4*)&sm.O2[oIdx(pa, n & 7, (hf * 4 + quad) ^ (n & 7))];
      if (pb >= 0) {
        uint4 qb = *(const uint4*)&sm.O2[oIdx(pb, n & 7, (hf * 4 + quad) ^ (n & 7))];
        qa = maxq(qa, qb);
      }
      FragU a; a.q = qa;
      if (hf == 0) a0 = MFMA16(a.v, Bd[jp * 2].v, a0, 0, 0, 0);
      else         a1 = MFMA16(a.v, Bd[jp * 2 + 1].v, a1, 0, 0, 0);
    }
  };

  auto dense_jp_pre = [&](int pa, const uint4* qpre, int jp, f32x4& a0, f32x4& a1) {
#pragma unroll
    for (int hf = 0; hf < 2; ++hf) {
      uint4 qa = *(const uint4*)&sm.O2[oIdx(pa, n & 7, (hf * 4 + quad) ^ (n & 7))];
      if (qpre) qa = maxq(qa, qpre[hf]);
      FragU a; a.q = qa;
      if (hf == 0) a0 = MFMA16(a.v, Bd[jp * 2].v, a0, 0, 0, 0);
      else         a1 = MFMA16(a.v, Bd[jp * 2 + 1].v, a1, 0, 0, 0);
    }
  };

  auto flush_out = [&](int bi, int t0, int cnt) {
    int vv = lane >> 3;
    int s0 = (lane & 7) * 8;
#pragma unroll
    for (int k = 0; k < 8; ++k) {
      int s = s0 + k;
      if (s < cnt) {
        float2 d = sm.obuf[bi][vv][s];
        *(float2*)(out + ((size_t)(vbase + vv) * nt + t0 + s) * 2) = d;
      }
    }
  };

  __syncthreads();

  // ---------------- phase 1: P ring init pos=2..21 ----------------
#pragma unroll
  for (int i = 0; i < 5; ++i) {
    int g = 2 + wid + 4 * i;
    RowD A = conv1s_row(g, 0, 0);
    RowD Bq = conv1s_row(g + 1, 0, 0);
    pool_store(A, Bq, g % 21);
  }
  __syncthreads();

  // ---------------- phase 2: O2 ring init a=2..17 ----------------
#pragma unroll
  for (int i = 0; i < 4; ++i) {
    int a = 2 + wid + 4 * i;
    f32x4 acc[4];
#pragma unroll
    for (int ct = 0; ct < 4; ++ct) acc[ct] = bcast4(b2v[ct]);
    conv2_acc(acc, a % 21, 0);
    conv2_acc(acc, (a + 2) % 21, 1);
    conv2_acc(acc, (a + 4) % 21, 2);
    o2_write(acc, a % 17);
  }
  __syncthreads();

  // ---------------- prologue A: j0(0)->17, j0(1)->18, row0(2)->21, chain accs ----
  RowD c1A = {};
  f32x4 accA[4] = {}, accB[4] = {};
  if (wid == 1) {
    RowD A = conv1s_row(0, 1, 0), Bq = conv1s_row(1, 0, 0);
    pool_store(A, Bq, 23);          // scratch (row0(0))
    lds_fence();
    f32x4 aj[4];
#pragma unroll
    for (int ct = 0; ct < 4; ++ct) aj[ct] = bcast4(b2v[ct]);
    conv2_acc(aj, 23, 0); conv2_acc(aj, 2, 1); conv2_acc(aj, 4, 2);
    o2_write(aj, 17);               // j0(0)
  } else if (wid == 2) {
    RowD A = conv1s_row(1, 1, 0), Bq = conv1s_row(2, 0, 0);
    pool_store(A, Bq, 1);           // scratch (row0(1)); ring slot 1 unused until step 0
    lds_fence();
    f32x4 aj[4];
#pragma unroll
    for (int ct = 0; ct < 4; ++ct) aj[ct] = bcast4(b2v[ct]);
    conv2_acc(aj, 1, 0); conv2_acc(aj, 3, 1); conv2_acc(aj, 5, 2);
    o2_write(aj, 18);               // j0(1)
  } else if (wid == 0) {
    RowD A = conv1s_row(2, 1, 0), Bq = conv1s_row(3, 0, 0);
    pool_store(A, Bq, 21);          // row0(2) -> R0(even)
  } else {
#pragma unroll
    for (int ct = 0; ct < 4; ++ct) accA[ct] = bcast4(b2v[ct]);
    conv2_acc(accA, 18, 0);         // j9(0) dw0
    conv2_acc(accA, 20, 1);         // j9(0) dw1
#pragma unroll
    for (int ct = 0; ct < 4; ++ct) accB[ct] = bcast4(b2v[ct]);
    conv2_acc(accB, 20, 0);         // j10(0) dw0
    c1A = conv1s_row(22, 0, 0);
  }
  __syncthreads();

  // ---------------- prologue B: Jpart(0) ----------------
  if (wid == 0) {
    f32x4 a0 = bcast4(d2bv), a1 = bcast4(0.f);
    dense_jp(17, 2, 0, a0, a1);     // jp0 = max(j0(0), j1(0))
    dense_jp(4, 6, 1, a0, a1);
    dense_jp(8, 10, 2, a0, a1);
    dense_jp(12, 14, 3, a0, a1);
    sm.JpartA[0][lane] = a0;
    sm.JpartB[0][lane] = a1;
  }
  __syncthreads();

  // ---------------- sequential steps (ONE barrier each) ----------------
  int tm21 = 0, tm17 = 0;
  for (int t = 0; t < nt; ++t) {
    const int sP22 = w21(tm21 + 22);
    const int sO16 = w17(tm17 + 16), sO18 = w17(tm17 + 18);
    const int tm21n = (tm21 + 1 == 21) ? 0 : tm21 + 1;
    const int tm17n = (tm17 + 1 == 17) ? 0 : tm17 + 1;
    const int sP18n = w21(tm21n + 18), sP20n = w21(tm21n + 20);

    if (wid == 3) {
      // ---- early off-chain loads (latency hidden under conv1) ----
      f32x4 jpA = sm.JpartA[t & 1][lane];
      f32x4 jpB = sm.JpartB[t & 1][lane];
      uint4 qj8[2];
#pragma unroll
      for (int hf = 0; hf < 2; ++hf)
        qj8[hf] = *(const uint4*)&sm.O2[oIdx(sO16, n & 7, (hf * 4 + quad) ^ (n & 7))];
      FragU fA18 = ld_P(sP18n);     // for accA(t+1) dw0
      FragU fA20 = ld_P(sP20n);     // for accA(t+1) dw1 / accB(t+1) dw0
      // ---- fresh conv1 (swapped; no LDS round-trip on the chain) ----
      RowD Bq = conv1s_row(t + 23, 0, 0);     // needs col t+24 (written step t-1)
      RowD Sg = conv1s_row(t + 24, 0, 1);
      uint4 w11 = pack4(relumax4(c1A.d0, Bq.d0), relumax4(c1A.d1, Bq.d1));
      uint4 w12 = pack4(relu4(Sg.d0), relu4(Sg.d1));
      p_store(w11, sP22);                     // ring write (readers >=2 steps later)
      c1A = Bq;                               // free carry for step t+1
      FragU f11 = bperm_frag(w11);            // pooled row 11 frag (reg transpose)
      FragU f12 = bperm_frag(w12);            // pooled row 12 frag
      // ---- fresh conv2 taps (dw0/dw1 carried from last step) ----
      conv2_accf(accA, f11, 2);               // j9 complete
      conv2_accf(accB, f11, 1);
      conv2_accf(accB, f12, 2);               // j10 complete
      o2_write(accA, sO18);                   // j9 -> ring
      o2_write(accB, 19);                     // j10 -> slot 19
      lds_fence();
      // ---- fresh dense + reduce + state ----
      f32x4 acc2 = bcast4(0.f), acc3 = bcast4(0.f);
      f32x4 acc4 = bcast4(0.f), acc5 = bcast4(0.f);
      dense_jp_pre(sO18, qj8, 4, acc2, acc3);                 // jp4 = max(j8, j9)
      dense_jp_pre(19, (const uint4*)nullptr, 5, acc4, acc5); // jp5 = j10
      float s0 = fmaxf(jpA[0] + jpB[0] + acc2[0] + acc3[0] + acc4[0] + acc5[0], 0.f) * wd1v;
      float s1 = fmaxf(jpA[1] + jpB[1] + acc2[1] + acc3[1] + acc4[1] + acc5[1], 0.f) * wd1v;
      float s2 = fmaxf(jpA[2] + jpB[2] + acc2[2] + acc3[2] + acc4[2] + acc5[2], 0.f) * wd1v;
      float s3 = fmaxf(jpA[3] + jpB[3] + acc2[3] + acc3[3] + acc4[3] + acc5[3], 0.f) * wd1v;
      s0 = rsum16(s0); s1 = rsum16(s1); s2 = rsum16(s2); s3 = rsum16(s3);
      if (quad < 2 && n < 4) {
        int veh = quad * 4 + n;
        float sv = (n == 0) ? s0 : (n == 1) ? s1 : (n == 2) ? s2 : s3;
        float accv = 10.f * (sv + bd1v) - 6.f;            // (MAXA-MINA)*x + MINA
        float np_s = pos_s + 0.02f * spd_s;               // scaled pos + DT*spd
        float nsp = spd_s * 40.f + 0.1f * accv;           // raw new speed
        pos_s = np_s; spd_s = nsp * 0.025f;
        float2 o2v; o2v.x = np_s * 200.f; o2v.y = nsp;
        sm.obuf[(t >> 6) & 1][veh][t & 63] = o2v;
        int ui = t + PAST; if (ui > ntw - 1) ui = ntw - 1;   // lead read in tail (R7 style)
        float2 ln = sm.lead[veh][ui];
        float x0 = ln.x * 0.005f - np_s;
        uint32_t wlo = pkbf(x0, spd_s);
        sm.Xcol[veh][(t + PAST) & 31][0] = wlo;
        sm.Xcol[veh][(t + PAST) & 31][1] = pkbf(ln.y * 0.025f, x0 - bf2f(wlo & 0xffffu));
      }
      // ---- next-step partial accs: register MFMA tail (loads hoisted above) ----
#pragma unroll
      for (int ct = 0; ct < 4; ++ct) accA[ct] = bcast4(b2v[ct]);
      conv2_accf(accA, fA18, 0);
      conv2_accf(accA, fA20, 1);
#pragma unroll
      for (int ct = 0; ct < 4; ++ct) accB[ct] = bcast4(b2v[ct]);
      conv2_accf(accB, fA20, 0);
    } else if (wid == 0) {
      // Jpart(t+1) = bias + jp0..jp3 (all operands >= 2 steps old)
      f32x4 a0 = bcast4(d2bv), a1 = bcast4(0.f);
      dense_jp(17 + ((t + 1) & 1), w17(tm17n + 2), 0, a0, a1);  // jp0 = max(j0, j1)
      dense_jp(w17(tm17n + 4), w17(tm17n + 6), 1, a0, a1);
      dense_jp(w17(tm17n + 8), w17(tm17n + 10), 2, a0, a1);
      dense_jp(w17(tm17n + 12), w17(tm17n + 14), 3, a0, a1);
      sm.JpartA[(t + 1) & 1][lane] = a0;
      sm.JpartB[(t + 1) & 1][lane] = a1;
    } else if (wid == 1) {
      // j0(t+2): row0 from R0 dbuf (written by wid2 last step) + old ring rows
      if ((t & 63) == 0 && t > 0) flush_out(((t >> 6) & 1) ^ 1, t - 64, 64);
      f32x4 aj[4];
#pragma unroll
      for (int ct = 0; ct < 4; ++ct) aj[ct] = bcast4(b2v[ct]);
      conv2_acc(aj, (t & 1) ? 23 : 21, 0);     // R0(t+2)
      conv2_acc(aj, w21(tm21 + 4), 1);
      conv2_acc(aj, w21(tm21 + 6), 2);
      o2_write(aj, 17 + (t & 1));              // J0(t+2)
    } else {
      // row0(t+3) -> R0 dbuf (cols t+2..t+5, all old)
      RowD A = conv1s_row(t + 3, 1, 0);
      RowD Bq = conv1s_row(t + 4, 0, 0);
      pool_store(A, Bq, (t & 1) ? 21 : 23);    // R0(t+3)
    }
    __syncthreads();

    tm21 = tm21n; tm17 = tm17n;
  }

  // final output flush
  if (wid == 1) {
    int t0 = (nt - 1) & ~63;
    flush_out(((nt - 1) >> 6) & 1, t0, nt - t0);
  }
}

extern "C" void kernel_launch(void* const* d_in, const int* in_sizes, int n_in,
                              void* d_out, int out_size, void* d_ws, size_t ws_size,
                              hipStream_t stream) {
  const float* lead = (const float*)d_in[0];
  const float* cur  = (const float*)d_in[1];
  // d_in[2] = mask (unused by reference)
  const float* c1w = (const float*)d_in[3];
  const float* c1b = (const float*)d_in[4];
  const float* c2w = (const float*)d_in[5];
  const float* c2b = (const float*)d_in[6];
  const float* d2w = (const float*)d_in[7];
  const float* d2b = (const float*)d_in[8];
  const float* d1w = (const float*)d_in[9];
  const float* d1b = (const float*)d_in[10];
  float* out = (float*)d_out;

  int nveh = in_sizes[1] / (PAST * 2);   // 4096
  int ntw  = in_sizes[2] / nveh;         // nt + PAST - 1 (<= NTW_MAX)
  int nt   = ntw - PAST + 1;             // 256
  int nblocks = nveh / 8;                // 512

  rnncf_kernel<<<nblocks, 256, 0, stream>>>(lead, cur, c1w, c1b, c2w, c2b,
                                            d2w, d2b, d1w, d1b, out, nt, ntw);
}